// Round 17
// baseline (101.800 us; speedup 1.0000x reference)
//
#include <hip/hip_runtime.h>
#include <math.h>

#define IN_DIM 256
#define OUT_DIM 256

typedef short short8 __attribute__((ext_vector_type(8)));
typedef short short4_t __attribute__((ext_vector_type(4)));
typedef float f32x4 __attribute__((ext_vector_type(4)));
typedef unsigned int u32;

static __device__ __forceinline__ short f2bf(float f) {
    union { float f; unsigned u; } c; c.f = f;
    unsigned r = (c.u + 0x7FFFu + ((c.u >> 16) & 1u)) >> 16;
    return (short)r;
}
static __device__ __forceinline__ float bf2f(short s) {
    union { unsigned u; float f; } c;
    c.u = ((u32)(unsigned short)s) << 16;
    return c.f;
}

// async global->LDS, 16B per lane. LDS dest must be linear in lane (base + lane*16).
static __device__ __forceinline__ void gload16(const void* g, void* l) {
    __builtin_amdgcn_global_load_lds(
        (const __attribute__((address_space(1))) u32*)g,
        (__attribute__((address_space(3))) u32*)l, 16, 0, 0);
}

// ============================ round-0 fp32 fastkan (fallback only) ============
template<int RT, int CT, int MODE>
__global__ __launch_bounds__(256) void fastkan_kernel(
    const float* __restrict__ X, const float* __restrict__ SW,
    const float* __restrict__ BW, const float* __restrict__ BB,
    float* __restrict__ OUT)
{
    constexpr int TRT = RT / 16;
    constexpr int TCT = CT / 16;
    __shared__ float aT[64][RT];
    __shared__ float bT[64][CT];
    const int t = threadIdx.x, tr = t >> 4, tc = t & 15;
    const int r0 = blockIdx.x * RT, c0 = blockIdx.y * CT;
    float acc[TRT][TCT];
#pragma unroll
    for (int a = 0; a < TRT; ++a)
#pragma unroll
        for (int b = 0; b < TCT; ++b) acc[a][b] = 0.f;

    for (int i0 = 0; i0 < IN_DIM; i0 += 8) {
        __syncthreads();
        constexpr int PER_A = (RT * 8) / 256;
#pragma unroll
        for (int j = 0; j < PER_A; ++j) {
            int p = j * 256 + t;
            int i = p & 7, r = p >> 3;
            float x = X[(size_t)(r0 + r) * IN_DIM + (i0 + i)];
#pragma unroll
            for (int g = 0; g < 8; ++g) {
                float z = (x - (-2.0f + (float)g * (4.0f / 7.0f))) * 1.75f;
                aT[i * 8 + g][r] = __expf(-z * z);
            }
        }
#pragma unroll
        for (int j = 0; j < (64 * CT) / 1024; ++j) {
            int p = j * 256 + t;
            int c4 = p % (CT / 4), kk = p / (CT / 4);
            *(float4*)&bT[kk][c4 * 4] =
                *(const float4*)&SW[(size_t)(i0 * 8 + kk) * OUT_DIM + (c0 + c4 * 4)];
        }
        __syncthreads();
#pragma unroll 8
        for (int kk = 0; kk < 64; ++kk) {
            float av[TRT], bv[TCT];
#pragma unroll
            for (int a = 0; a < TRT; ++a) av[a] = aT[kk][tr * TRT + a];
#pragma unroll
            for (int b = 0; b < TCT; ++b) bv[b] = bT[kk][tc * TCT + b];
#pragma unroll
            for (int a = 0; a < TRT; ++a)
#pragma unroll
                for (int b = 0; b < TCT; ++b)
                    acc[a][b] = fmaf(av[a], bv[b], acc[a][b]);
        }
    }
    for (int i0 = 0; i0 < IN_DIM; i0 += 64) {
        __syncthreads();
#pragma unroll
        for (int j = 0; j < (RT * 64) / 1024; ++j) {
            int p = j * 256 + t;
            int i4 = p & 15, r = p >> 4;
            float4 xv = *(const float4*)&X[(size_t)(r0 + r) * IN_DIM + (i0 + i4 * 4)];
            const float* xe = &xv.x;
#pragma unroll
            for (int e = 0; e < 4; ++e) {
                float x = xe[e];
                aT[i4 * 4 + e][r] = x / (1.f + __expf(-x));
            }
        }
#pragma unroll
        for (int j = 0; j < (64 * CT) / 1024; ++j) {
            int p = j * 256 + t;
            int c4 = p % (CT / 4), kk = p / (CT / 4);
            *(float4*)&bT[kk][c4 * 4] =
                *(const float4*)&BW[(size_t)(i0 + kk) * OUT_DIM + (c0 + c4 * 4)];
        }
        __syncthreads();
#pragma unroll 8
        for (int kk = 0; kk < 64; ++kk) {
            float av[TRT], bv[TCT];
#pragma unroll
            for (int a = 0; a < TRT; ++a) av[a] = aT[kk][tr * TRT + a];
#pragma unroll
            for (int b = 0; b < TCT; ++b) bv[b] = bT[kk][tc * TCT + b];
#pragma unroll
            for (int a = 0; a < TRT; ++a)
#pragma unroll
                for (int b = 0; b < TCT; ++b)
                    acc[a][b] = fmaf(av[a], bv[b], acc[a][b]);
        }
    }
#pragma unroll
    for (int a = 0; a < TRT; ++a) {
        int r = r0 + tr * TRT + a;
#pragma unroll
        for (int b = 0; b < TCT; ++b) {
            int c = c0 + tc * TCT + b;
            float v = acc[a][b] + BB[c];
            if (MODE == 1) v *= 0.17677669529663687f;
            if (MODE == 2) v = 1.f / (1.f + __expf(-v));
            OUT[(size_t)r * OUT_DIM + c] = v;
        }
    }
}

// ============================ split-K fastkan (o-layer + fallback q/g) ========
__global__ __launch_bounds__(256) void fastkan_splitk(
    const float* __restrict__ X,
    const float* __restrict__ SW0, const float* __restrict__ BW0,
    const float* __restrict__ SW1, const float* __restrict__ BW1,
    float* __restrict__ PART)
{
    __shared__ float aT[128][65];
    __shared__ float bT[64][33];

    const int t = threadIdx.x;
    const int tr = t >> 4, tc = t & 15;
    const int c0 = blockIdx.x * 32;
    const int kc = blockIdx.y;
    const int z = blockIdx.z;
    const float* SW = z ? SW1 : SW0;
    const float* BW = z ? BW1 : BW0;

    float acc[8][2];
#pragma unroll
    for (int a = 0; a < 8; ++a) { acc[a][0] = 0.f; acc[a][1] = 0.f; }

    for (int sub = 0; sub < 4; ++sub) {
        const int k0 = kc * 256 + sub * 64;
        __syncthreads();
        if (kc < 8) {
            const int i0 = kc * 32 + sub * 8;
#pragma unroll
            for (int it = 0; it < 4; ++it) {
                int p = it * 256 + t;
                int row = p & 127, i = p >> 7;
                float x = X[(size_t)row * 256 + i0 + i];
#pragma unroll
                for (int g = 0; g < 8; ++g) {
                    float zz = (x - (-2.0f + (float)g * (4.0f / 7.0f))) * 1.75f;
                    aT[row][i * 8 + g] = __expf(-zz * zz);
                }
            }
        } else {
            const int f0 = sub * 64;
            int row = t >> 1, seg = t & 1;
            const float* xr = &X[(size_t)row * 256 + f0 + seg * 32];
#pragma unroll
            for (int j4 = 0; j4 < 8; ++j4) {
                float4 xv = *(const float4*)&xr[j4 * 4];
                const float* xe = &xv.x;
#pragma unroll
                for (int e = 0; e < 4; ++e) {
                    float x = xe[e];
                    aT[row][seg * 32 + j4 * 4 + e] = x / (1.f + __expf(-x));
                }
            }
        }
        {
            const float* Wsrc = (kc < 8) ? &SW[(size_t)k0 * 256] : &BW[(size_t)(k0 - 2048) * 256];
#pragma unroll
            for (int it = 0; it < 2; ++it) {
                int p = it * 256 + t;
                int kk = p >> 3, c4 = p & 7;
                float4 v = *(const float4*)&Wsrc[(size_t)kk * 256 + c0 + c4 * 4];
                bT[kk][c4 * 4 + 0] = v.x; bT[kk][c4 * 4 + 1] = v.y;
                bT[kk][c4 * 4 + 2] = v.z; bT[kk][c4 * 4 + 3] = v.w;
            }
        }
        __syncthreads();
#pragma unroll 8
        for (int kk = 0; kk < 64; ++kk) {
            float av[8], bv[2];
#pragma unroll
            for (int a = 0; a < 8; ++a) av[a] = aT[tr * 8 + a][kk];
            bv[0] = bT[kk][tc * 2 + 0];
            bv[1] = bT[kk][tc * 2 + 1];
#pragma unroll
            for (int a = 0; a < 8; ++a) {
                acc[a][0] = fmaf(av[a], bv[0], acc[a][0]);
                acc[a][1] = fmaf(av[a], bv[1], acc[a][1]);
            }
        }
    }
#pragma unroll
    for (int a = 0; a < 8; ++a) {
        int r = tr * 8 + a;
        float* dst = &PART[((size_t)(z * 9 + kc) * 128 + r) * 256 + c0 + tc * 2];
        dst[0] = acc[a][0];
        dst[1] = acc[a][1];
    }
}

template<int MODE>
__global__ __launch_bounds__(256) void reduce_kernel(
    const float* __restrict__ PART, const float* __restrict__ BB, float* __restrict__ OUT)
{
    const int r = blockIdx.x, t = threadIdx.x;
    float s = 0.f;
#pragma unroll
    for (int kc = 0; kc < 9; ++kc)
        s += PART[((size_t)kc * 128 + r) * 256 + t];
    float v = s + BB[t];
    if (MODE == 1) v *= 0.17677669529663687f;
    if (MODE == 2) v = 1.f / (1.f + __expf(-v));
    OUT[(size_t)r * 256 + t] = v;
}

// fallback q/g reduce
template<int WB>
__global__ __launch_bounds__(256) void reduce_qg(
    const float* __restrict__ PART, const float* __restrict__ QBB,
    const float* __restrict__ GBB, float* __restrict__ WQ, float* __restrict__ GB,
    short* __restrict__ WQb)
{
    const int r = blockIdx.x, t = threadIdx.x, z = blockIdx.y;
    const float* P = PART + (size_t)z * 9 * 128 * 256;
    float s = 0.f;
#pragma unroll
    for (int kc = 0; kc < 9; ++kc)
        s += P[((size_t)kc * 128 + r) * 256 + t];
    if (z == 0) {
        float v = (s + QBB[t]) * 0.17677669529663687f;
        WQ[(size_t)r * 256 + t] = v;
        if (WB) WQb[(size_t)r * 256 + t] = f2bf(v);
    } else {
        float v = s + GBB[t];
        GB[(size_t)r * 256 + t] = 1.f / (1.f + __expf(-v));
    }
}

// ============================ weight prep (fallback standalone) ===============
__global__ __launch_bounds__(256) void prep_kernel(
    const float* __restrict__ SWk, const float* __restrict__ BWk, short* __restrict__ Bk,
    const float* __restrict__ SWv, const float* __restrict__ BWv, short* __restrict__ Bv)
{
    __shared__ float tile[64][65];
    const int t = threadIdx.x;
    const int kk0 = blockIdx.x * 64;
    const int c0 = blockIdx.y * 64;
    const float* SW = blockIdx.z ? SWv : SWk;
    const float* BW = blockIdx.z ? BWv : BWk;
    short* Bdst = blockIdx.z ? Bv : Bk;

#pragma unroll
    for (int j = 0; j < 4; ++j) {
        int p = j * 256 + t;
        int lr = p >> 4, lc4 = p & 15;
        float4 v;
        if (kk0 < 2048) v = *(const float4*)&SW[(size_t)(kk0 + lr) * 256 + c0 + lc4 * 4];
        else            v = *(const float4*)&BW[(size_t)(kk0 - 2048 + lr) * 256 + c0 + lc4 * 4];
        tile[lr][lc4 * 4 + 0] = v.x; tile[lr][lc4 * 4 + 1] = v.y;
        tile[lr][lc4 * 4 + 2] = v.z; tile[lr][lc4 * 4 + 3] = v.w;
    }
    __syncthreads();
#pragma unroll
    for (int j = 0; j < 4; ++j) {
        int p = j * 256 + t;
        int lc = p >> 4, lk4 = p & 15;
        short4_t s;
#pragma unroll
        for (int e = 0; e < 4; ++e) s[e] = f2bf(tile[lk4 * 4 + e][lc]);
        *(short4_t*)&Bdst[(size_t)(c0 + lc) * 2304 + kk0 + lk4 * 4] = s;
    }
}

// ============================ basis precompute (fallback standalone) ==========
__global__ __launch_bounds__(256) void basis_gen2(
    const float* __restrict__ K, const float* __restrict__ V,
    short* __restrict__ A0, short* __restrict__ A1)
{
    const float* X = blockIdx.y ? V : K;
    short* A = blockIdx.y ? A1 : A0;
    const int row = blockIdx.x;
    const int t = threadIdx.x;
    float x = X[(size_t)row * 256 + t];
    short8 s;
#pragma unroll
    for (int g = 0; g < 8; ++g) {
        float z = (x - (-2.0f + (float)g * (4.0f / 7.0f))) * 1.75f;
        s[g] = f2bf(__expf(-z * z));
    }
    *(short8*)&A[(size_t)row * 2304 + t * 8] = s;
    if (t < 32) {
        const float* xr = &X[(size_t)row * 256 + t * 8];
        short8 sl;
#pragma unroll
        for (int e2 = 0; e2 < 2; ++e2) {
            float4 xv = *(const float4*)&xr[e2 * 4];
            const float* xe = &xv.x;
#pragma unroll
            for (int e = 0; e < 4; ++e) {
                float xx = xe[e];
                sl[e2 * 4 + e] = f2bf(xx / (1.f + __expf(-xx)));
            }
        }
        *(short8*)&A[(size_t)row * 2304 + 2048 + t * 8] = sl;
    }
}

// ============================ fused prep + basis (k,v,q basis; k,v,q,g weights)
__global__ __launch_bounds__(256) void prep_basis(
    const float* __restrict__ K, const float* __restrict__ V, const float* __restrict__ Q,
    short* __restrict__ A0, short* __restrict__ A1, short* __restrict__ Aq,
    const float* __restrict__ SWk, const float* __restrict__ BWk, short* __restrict__ Bk,
    const float* __restrict__ SWv, const float* __restrict__ BWv, short* __restrict__ Bv,
    const float* __restrict__ SWq, const float* __restrict__ BWq, short* __restrict__ Bq,
    const float* __restrict__ SWg, const float* __restrict__ BWg, short* __restrict__ Bg)
{
    __shared__ float tile[64][65];
    const int bid = blockIdx.x;
    const int t = threadIdx.x;
    if (bid < 16512) {
        const int m = bid >> 13;
        const float* X = (m == 0) ? K : ((m == 1) ? V : Q);
        short* A = (m == 0) ? A0 : ((m == 1) ? A1 : Aq);
        const int row = bid & 8191;
        float x = X[(size_t)row * 256 + t];
        short8 s;
#pragma unroll
        for (int g = 0; g < 8; ++g) {
            float z = (x - (-2.0f + (float)g * (4.0f / 7.0f))) * 1.75f;
            s[g] = f2bf(__expf(-z * z));
        }
        *(short8*)&A[(size_t)row * 2304 + t * 8] = s;
        if (t < 32) {
            const float* xr = &X[(size_t)row * 256 + t * 8];
            short8 sl;
#pragma unroll
            for (int e2 = 0; e2 < 2; ++e2) {
                float4 xv = *(const float4*)&xr[e2 * 4];
                const float* xe = &xv.x;
#pragma unroll
                for (int e = 0; e < 4; ++e) {
                    float xx = xe[e];
                    sl[e2 * 4 + e] = f2bf(xx / (1.f + __expf(-xx)));
                }
            }
            *(short8*)&A[(size_t)row * 2304 + 2048 + t * 8] = sl;
        }
        return;
    }
    const int p = bid - 16512;
    const int mat = p / 144;
    const int q = p % 144;
    const int kk0 = (q >> 2) * 64;
    const int c0 = (q & 3) * 64;
    const float* SW = (mat == 0) ? SWk : ((mat == 1) ? SWv : ((mat == 2) ? SWq : SWg));
    const float* BW = (mat == 0) ? BWk : ((mat == 1) ? BWv : ((mat == 2) ? BWq : BWg));
    short* Bdst     = (mat == 0) ? Bk  : ((mat == 1) ? Bv  : ((mat == 2) ? Bq  : Bg));

#pragma unroll
    for (int j = 0; j < 4; ++j) {
        int pp = j * 256 + t;
        int lr = pp >> 4, lc4 = pp & 15;
        float4 v;
        if (kk0 < 2048) v = *(const float4*)&SW[(size_t)(kk0 + lr) * 256 + c0 + lc4 * 4];
        else            v = *(const float4*)&BW[(size_t)(kk0 - 2048 + lr) * 256 + c0 + lc4 * 4];
        tile[lr][lc4 * 4 + 0] = v.x; tile[lr][lc4 * 4 + 1] = v.y;
        tile[lr][lc4 * 4 + 2] = v.z; tile[lr][lc4 * 4 + 3] = v.w;
    }
    __syncthreads();
#pragma unroll
    for (int j = 0; j < 4; ++j) {
        int pp = j * 256 + t;
        int lc = pp >> 4, lk4 = pp & 15;
        short4_t s;
#pragma unroll
        for (int e = 0; e < 4; ++e) s[e] = f2bf(tile[lk4 * 4 + e][lc]);
        *(short4_t*)&Bdst[(size_t)(c0 + lc) * 2304 + kk0 + lk4 * 4] = s;
    }
}

// ============================ STAGE 2: uniform 9-step split-K4 gemm ===========
// bid < 1024: kv gemm (x=bid&63, y=(bid>>6)&1, zz=bid>>7: mat=zz>>2, kh=zz&3)
// bid >= 1024: q/g gemm (p=bid-1024: layer=p>>3, y=(p>>2)&1, kh=p&3; r0=0)
// All blocks: 9 K-steps, 128x128 tile, bf16 quarter-partials at base+kh*stride;
// kh=0 carries bias; q-layer halves carry 1/sqrt(32).
__global__ __launch_bounds__(256) void stage2(
    const short* __restrict__ A0, const short* __restrict__ A1, const short* __restrict__ Aq,
    const short* __restrict__ Bk, const short* __restrict__ Bv,
    const short* __restrict__ Bq, const short* __restrict__ Bg,
    const float* __restrict__ BBk, const float* __restrict__ BBv,
    const float* __restrict__ QBB, const float* __restrict__ GBB,
    short* __restrict__ GPk, short* __restrict__ GPv,
    short* __restrict__ GPq, short* __restrict__ GPg)
{
    __shared__ __align__(16) short Al[128 * 64];
    __shared__ __align__(16) short Bl[128 * 64];

    const int bid = blockIdx.x;
    const int t = threadIdx.x;
    const int lane = t & 63, wid = t >> 6;
    const int wm = wid >> 1, wn = wid & 1;
    const int lrow = lane & 15;
    const int lkb = (lane >> 4) * 16;

    const short* A;
    const short* B2;
    int r0, c0, kh, which;            // which: 0=k 1=v 2=q 3=g
    if (bid < 1024) {
        const int zz = bid >> 7;
        which = zz >> 2;              // 0 or 1
        kh = zz & 3;
        A  = which ? A1 : A0;
        B2 = which ? Bv : Bk;
        r0 = (bid & 63) * 128;
        c0 = ((bid >> 6) & 1) * 128;
    } else {
        const int p = bid - 1024;
        which = 2 + (p >> 3);         // 2 or 3
        kh = p & 3;
        A = Aq;
        B2 = (which == 3) ? Bg : Bq;
        r0 = 0;
        c0 = ((p >> 2) & 1) * 128;
    }
    const int kbase = kh * 576;

    f32x4 acc[4][4];
#pragma unroll
    for (int a = 0; a < 4; ++a)
#pragma unroll
        for (int c = 0; c < 4; ++c) acc[a][c] = (f32x4){0.f, 0.f, 0.f, 0.f};

    for (int st = 0; st < 9; ++st) {
        const int k0 = kbase + st * 64;
        __syncthreads();
#pragma unroll
        for (int i = 0; i < 4; ++i) {
            int f = i * 256 + t;
            int row = f >> 3, kg = f & 7;
            gload16(&A[(size_t)(r0 + row) * 2304 + k0 + kg * 8], (char*)Al + f * 16);
        }
#pragma unroll
        for (int i = 0; i < 4; ++i) {
            int f = i * 256 + t;
            int c = f >> 3, kg = f & 7;
            gload16(&B2[(size_t)(c0 + c) * 2304 + k0 + kg * 8], (char*)Bl + f * 16);
        }
        __syncthreads();
#pragma unroll
        for (int kf = 0; kf < 2; ++kf) {
            short8 af[4], bf[4];
#pragma unroll
            for (int a = 0; a < 4; ++a) {
                int R = wm * 64 + a * 16 + lrow;
                af[a] = *(short8*)((char*)Al + R * 128 + kf * 64 + lkb);
            }
#pragma unroll
            for (int c = 0; c < 4; ++c) {
                int C = wn * 64 + c * 16 + lrow;
                bf[c] = *(short8*)((char*)Bl + C * 128 + kf * 64 + lkb);
            }
#pragma unroll
            for (int a = 0; a < 4; ++a)
#pragma unroll
                for (int c = 0; c < 4; ++c)
                    acc[a][c] = __builtin_amdgcn_mfma_f32_16x16x32_bf16(af[a], bf[c], acc[a][c], 0, 0, 0);
        }
    }

    short* OUT;
    const float* BB;
    float scale = 1.0f;
    if (which == 0)      { OUT = GPk + (size_t)kh * 2097152; BB = BBk; }
    else if (which == 1) { OUT = GPv + (size_t)kh * 2097152; BB = BBv; }
    else if (which == 2) { OUT = GPq + (size_t)kh * 32768; BB = QBB; scale = 0.17677669529663687f; }
    else                 { OUT = GPg + (size_t)kh * 32768; BB = GBB; }

#pragma unroll
    for (int a = 0; a < 4; ++a)
#pragma unroll
        for (int c = 0; c < 4; ++c) {
            int col = c0 + wn * 64 + c * 16 + lrow;
            float bias = (kh == 0) ? BB[col] : 0.f;
#pragma unroll
            for (int j = 0; j < 4; ++j) {
                int row = r0 + wm * 64 + a * 16 + (lane >> 4) * 4 + j;
                OUT[(size_t)row * 256 + col] = f2bf((acc[a][c][j] + bias) * scale);
            }
        }
}

// ============================ 64-tile GEMM (fallback, reg-staged, fp32 out) ===
__global__ __launch_bounds__(256) void gemm_tile(
    const short* __restrict__ A, const short* __restrict__ B2,
    const float* __restrict__ BB, float* __restrict__ OUT)
{
    __shared__ __align__(16) short A_l[64 * 64];
    __shared__ __align__(16) short B_l[64 * 64];
    char* ab = (char*)A_l;
    char* bb = (char*)B_l;

    const int t = threadIdx.x;
    const int r0 = blockIdx.x * 64;
    const int c0 = blockIdx.y * 64;
    const int lane = t & 63;
    const int wid = t >> 6;
    const int wm = wid >> 1, wn = wid & 1;
    const int lrow = lane & 15;
    const int lkb = (lane >> 4) * 16;

    f32x4 acc[2][2];
#pragma unroll
    for (int a = 0; a < 2; ++a)
#pragma unroll
        for (int c = 0; c < 2; ++c) acc[a][c] = (f32x4){0.f, 0.f, 0.f, 0.f};

    for (int st = 0; st < 36; ++st) {
        const int k0 = st * 64;
        __syncthreads();
#pragma unroll
        for (int it = 0; it < 2; ++it) {
            int p = it * 256 + t;
            int row = p >> 3, kg = p & 7;
            short8 s = *(const short8*)&A[(size_t)(r0 + row) * 2304 + k0 + kg * 8];
            int off = (row * 128 + kg * 16) ^ ((row & 7) << 4);
            *(short8*)(ab + off) = s;
        }
#pragma unroll
        for (int it = 0; it < 2; ++it) {
            int p = it * 256 + t;
            int c = p >> 3, kg = p & 7;
            short8 s = *(const short8*)&B2[(size_t)(c0 + c) * 2304 + k0 + kg * 8];
            int off = (c * 128 + kg * 16) ^ ((c & 7) << 4);
            *(short8*)(bb + off) = s;
        }
        __syncthreads();
#pragma unroll
        for (int kf = 0; kf < 2; ++kf) {
            short8 af[2], bf[2];
#pragma unroll
            for (int a = 0; a < 2; ++a) {
                int R = wm * 32 + a * 16 + lrow;
                int off = (R * 128 + kf * 64 + lkb) ^ ((R & 7) << 4);
                af[a] = *(short8*)(ab + off);
            }
#pragma unroll
            for (int c = 0; c < 2; ++c) {
                int R = wn * 32 + c * 16 + lrow;
                int off = (R * 128 + kf * 64 + lkb) ^ ((R & 7) << 4);
                bf[c] = *(short8*)(bb + off);
            }
#pragma unroll
            for (int a = 0; a < 2; ++a)
#pragma unroll
                for (int c = 0; c < 2; ++c)
                    acc[a][c] = __builtin_amdgcn_mfma_f32_16x16x32_bf16(af[a], bf[c], acc[a][c], 0, 0, 0);
        }
    }
#pragma unroll
    for (int a = 0; a < 2; ++a)
#pragma unroll
        for (int c = 0; c < 2; ++c) {
            int col = c0 + wn * 32 + c * 16 + (lane & 15);
            float bias = BB[col];
#pragma unroll
            for (int j = 0; j < 4; ++j) {
                int row = r0 + wm * 32 + a * 16 + (lane >> 4) * 4 + j;
                OUT[(size_t)row * 256 + col] = acc[a][c][j] + bias;
            }
        }
}

// ============================ MFMA attention (4-way summed Q/K/V staging) =====
__global__ __launch_bounds__(256) void attn_mfma(
    const short* __restrict__ GPq, const short* __restrict__ GPk, const short* __restrict__ GPv,
    float* __restrict__ OPART, float* __restrict__ LPART)
{
    __shared__ __align__(16) short Ql[128 * 32];   // [q][d] linear
    __shared__ __align__(16) short Kl[64 * 32];    // [s][d] linear
    __shared__ __align__(16) short Vt[32 * 64];    // [d][s] swizzled
    __shared__ __align__(16) short El[128 * 64];   // [q][s] swizzled
    char* ql = (char*)Ql; char* kl = (char*)Kl;
    char* vt = (char*)Vt; char* el = (char*)El;

    const int t = threadIdx.x, lane = t & 63, w = t >> 6;
    const int ch = blockIdx.x, h = blockIdx.y, s0 = ch * 64;
    const int lr = lane & 15, lg = lane >> 4;

    {
        // Q = sum of 4 quarter-partials (scale & bias folded)
#pragma unroll
        for (int i = 0; i < 2; ++i) {
            int f = i * 256 + t;
            int row = f >> 2, d8 = (f & 3) * 8;
            size_t qoff = (size_t)row * 256 + h * 32 + d8;
            float acc[8];
#pragma unroll
            for (int e = 0; e < 8; ++e) acc[e] = 0.f;
#pragma unroll
            for (int kh = 0; kh < 4; ++kh) {
                short8 qp = *(const short8*)&GPq[qoff + (size_t)kh * 32768];
#pragma unroll
                for (int e = 0; e < 8; ++e) acc[e] += bf2f(qp[e]);
            }
            short8 qs;
#pragma unroll
            for (int e = 0; e < 8; ++e) qs[e] = f2bf(acc[e]);
            *(short8*)(ql + f * 16) = qs;
        }
        int s = t >> 2, d8 = (t & 3) * 8;
        size_t off = (size_t)(s0 + s) * 256 + h * 32 + d8;
        float ka[8], va[8];
#pragma unroll
        for (int e = 0; e < 8; ++e) { ka[e] = 0.f; va[e] = 0.f; }
#pragma unroll
        for (int kh = 0; kh < 4; ++kh) {
            short8 kp = *(const short8*)&GPk[off + (size_t)kh * 2097152];
            short8 vp = *(const short8*)&GPv[off + (size_t)kh * 2097152];
#pragma unroll
            for (int e = 0; e < 8; ++e) { ka[e] += bf2f(kp[e]); va[e] += bf2f(vp[e]); }
        }
        short8 ks;
#pragma unroll
        for (int e = 0; e < 8; ++e) ks[e] = f2bf(ka[e]);
        *(short8*)(kl + t * 16) = ks;
#pragma unroll
        for (int e = 0; e < 8; ++e) {
            int d = d8 + e;
            *(short*)(vt + ((d * 128 + s * 2) ^ ((d & 7) << 4))) = f2bf(va[e]);
        }
    }
    __syncthreads();

#pragma unroll
    for (int i = 0; i < 2; ++i) {
        const int q = (w * 2 + i) * 16 + lr;
        short8 bq = *(short8*)(ql + q * 64 + lg * 16);
        float ls = 0.f;
#pragma unroll
        for (int j = 0; j < 4; ++j) {
            short8 ak = *(short8*)(kl + (j * 16 + lr) * 64 + lg * 16);
            f32x4 sc = {0.f, 0.f, 0.f, 0.f};
            sc = __builtin_amdgcn_mfma_f32_16x16x32_bf16(ak, bq, sc, 0, 0, 0);
            short4_t ep;
#pragma unroll
            for (int jj = 0; jj < 4; ++jj) {
                float e = __expf(sc[jj] - 16.0f);
                ls += e;
                ep[jj] = f2bf(e);
            }
            int sb = j * 16 + lg * 4;
            *(short4_t*)(el + ((q * 128 + sb * 2) ^ ((q & 7) << 4))) = ep;
        }
        ls += __shfl_xor(ls, 16);
        ls += __shfl_xor(ls, 32);
        if (lg == 0)
            LPART[(size_t)(ch * 8 + h) * 128 + (w * 2 + i) * 16 + lr] = ls;
    }
    __syncthreads();

    f32x4 oacc[2][2];
#pragma unroll
    for (int i = 0; i < 2; ++i)
#pragma unroll
        for (int d = 0; d < 2; ++d) oacc[i][d] = (f32x4){0.f, 0.f, 0.f, 0.f};
#pragma unroll
    for (int kf = 0; kf < 2; ++kf) {
        short8 ea[2], vb[2];
#pragma unroll
        for (int i = 0; i < 2; ++i) {
            int q = (w * 2 + i) * 16 + lr;
            ea[i] = *(short8*)(el + ((q * 128 + kf * 64 + lg * 16) ^ ((q & 7) << 4)));
        }
#pragma unroll
        for (int d = 0; d < 2; ++d) {
            int dd = d * 16 + lr;
            vb[d] = *(short8*)(vt + ((dd * 128 + kf * 64 + lg * 16) ^ ((dd & 7) << 4)));
        }
#pragma unroll
        for (int i = 0; i < 2; ++i)
#pragma unroll
            for (int d = 0; d < 2; ++d)
                oacc[i][d] = __builtin_amdgcn_mfma_f32_16x16x32_bf16(ea[i], vb[d], oacc[i][d], 0, 0, 0);
    }
#pragma unroll
    for (int i = 0; i < 2; ++i)
#pragma unroll
        for (int d = 0; d < 2; ++d) {
            int dd = d * 16 + lr;
#pragma unroll
            for (int j = 0; j < 4; ++j) {
                int q = (w * 2 + i) * 16 + lg * 4 + j;
                OPART[((size_t)(ch * 8 + h) * 128 + q) * 32 + dd] = oacc[i][d][j];
            }
        }
}

// ============================ parallel attention reduce (gate from g quarters) =
__global__ __launch_bounds__(256) void attn_reduce2(
    const float* __restrict__ OPART, const float* __restrict__ LPART,
    const short* __restrict__ GPg, float* __restrict__ OMID)
{
    __shared__ float so[8][33];
    __shared__ float sl[8];
    const int b = blockIdx.x, h = blockIdx.y;
    const int t = threadIdx.x;
    const int d = t & 31, part = t >> 5;
    float o = 0.f, l = 0.f;
#pragma unroll 4
    for (int cc = 0; cc < 16; ++cc) {
        int ch = part * 16 + cc;
        o += OPART[((size_t)(ch * 8 + h) * 128 + b) * 32 + d];
        l += LPART[(size_t)(ch * 8 + h) * 128 + b];
    }
    so[part][d] = o;
    if (d == 0) sl[part] = l;
    __syncthreads();
    if (t < 32) {
        float oo = 0.f, ll = 0.f;
#pragma unroll
        for (int p = 0; p < 8; ++p) { oo += so[p][t]; ll += sl[p]; }
        int idx = b * 256 + h * 32 + t;
        float gs = 0.f;
#pragma unroll
        for (int kh = 0; kh < 4; ++kh) gs += bf2f(GPg[idx + (size_t)kh * 32768]);
        float g = 1.f / (1.f + __expf(-gs));
        OMID[idx] = g * (oo / ll);
    }
}

// ============================ fp32 chunked attention (fallback) ===============
__global__ __launch_bounds__(256) void attn_chunk(
    const float* __restrict__ WQ, const float* __restrict__ WK, const float* __restrict__ WV,
    float* __restrict__ OPART, float* __restrict__ LPART)
{
    __shared__ float sWQ[128][33];
    __shared__ float sWK[64][33];
    __shared__ float sWV[64][33];
    __shared__ float sE[128][66];
    __shared__ float lred[128][16];

    const int t = threadIdx.x;
    const int ch = blockIdx.x;
    const int h = blockIdx.y;
    const int s0 = ch * 64;

    {
        int b = t >> 1, seg = t & 1;
        const float* src = &WQ[(size_t)b * 256 + h * 32 + seg * 16];
#pragma unroll
        for (int j = 0; j < 4; ++j) {
            float4 v = *(const float4*)&src[j * 4];
            sWQ[b][seg * 16 + j * 4 + 0] = v.x; sWQ[b][seg * 16 + j * 4 + 1] = v.y;
            sWQ[b][seg * 16 + j * 4 + 2] = v.z; sWQ[b][seg * 16 + j * 4 + 3] = v.w;
        }
        if (t < 128) {
            int s = t >> 1; seg = t & 1;
            const float* sk = &WK[(size_t)(s0 + s) * 256 + h * 32 + seg * 16];
#pragma unroll
            for (int j = 0; j < 4; ++j) {
                float4 v = *(const float4*)&sk[j * 4];
                sWK[s][seg * 16 + j * 4 + 0] = v.x; sWK[s][seg * 16 + j * 4 + 1] = v.y;
                sWK[s][seg * 16 + j * 4 + 2] = v.z; sWK[s][seg * 16 + j * 4 + 3] = v.w;
            }
        } else {
            int t2 = t - 128;
            int s = t2 >> 1; seg = t2 & 1;
            const float* sv = &WV[(size_t)(s0 + s) * 256 + h * 32 + seg * 16];
#pragma unroll
            for (int j = 0; j < 4; ++j) {
                float4 v = *(const float4*)&sv[j * 4];
                sWV[s][seg * 16 + j * 4 + 0] = v.x; sWV[s][seg * 16 + j * 4 + 1] = v.y;
                sWV[s][seg * 16 + j * 4 + 2] = v.z; sWV[s][seg * 16 + j * 4 + 3] = v.w;
            }
        }
    }
    __syncthreads();

    const int tr = t >> 4, tc = t & 15;
    {
        float acc[8][4];
#pragma unroll
        for (int a = 0; a < 8; ++a)
#pragma unroll
            for (int b = 0; b < 4; ++b) acc[a][b] = 0.f;
#pragma unroll 4
        for (int kk = 0; kk < 32; ++kk) {
            float av[8], bv[4];
#pragma unroll
            for (int a = 0; a < 8; ++a) av[a] = sWQ[tr * 8 + a][kk];
#pragma unroll
            for (int b = 0; b < 4; ++b) bv[b] = sWK[tc * 4 + b][kk];
#pragma unroll
            for (int a = 0; a < 8; ++a)
#pragma unroll
                for (int b = 0; b < 4; ++b) acc[a][b] = fmaf(av[a], bv[b], acc[a][b]);
        }
#pragma unroll
        for (int a = 0; a < 8; ++a) {
            float lp = 0.f;
#pragma unroll
            for (int b = 0; b < 4; ++b) {
                float e = __expf(acc[a][b] - 16.0f);
                sE[tr * 8 + a][tc * 4 + b] = e;
                lp += e;
            }
            lred[tr * 8 + a][tc] = lp;
        }
    }
    __syncthreads();
    if (t < 128) {
        float l = 0.f;
#pragma unroll
        for (int j = 0; j < 16; ++j) l += lred[t][j];
        LPART[(size_t)(ch * 8 + h) * 128 + t] = l;
    }

    {
        float acc2[8][2];
#pragma unroll
        for (int a = 0; a < 8; ++a) { acc2[a][0] = 0.f; acc2[a][1] = 0.f; }
#pragma unroll 4
        for (int kk = 0; kk < 64; ++kk) {
            float av[8], bv[2];
#pragma unroll
            for (int a = 0; a < 8; ++a) av[a] = sE[tr * 8 + a][kk];
            bv[0] = sWV[kk][tc * 2 + 0];
            bv[1] = sWV[kk][tc * 2 + 1];
#pragma unroll
            for (int a = 0; a < 8; ++a) {
                acc2[a][0] = fmaf(av[a], bv[0], acc2[a][0]);
                acc2[a][1] = fmaf(av[a], bv[1], acc2[a][1]);
            }
        }
#pragma unroll
        for (int a = 0; a < 8; ++a) {
            int b = tr * 8 + a;
            float* dst = &OPART[((size_t)(ch * 8 + h) * 128 + b) * 32 + tc * 2];
            dst[0] = acc2[a][0];
            dst[1] = acc2[a][1];
        }
    }
}

__global__ __launch_bounds__(256) void attn_reduce(
    const float* __restrict__ OPART, const float* __restrict__ LPART,
    const float* __restrict__ G, float* __restrict__ OMID)
{
    const int b = blockIdx.x;
    const int t = threadIdx.x;
    const int h = t >> 5, d = t & 31;
    float o = 0.f, l = 0.f;
    for (int ch = 0; ch < 128; ++ch) {
        o += OPART[((size_t)(ch * 8 + h) * 128 + b) * 32 + d];
        l += LPART[(size_t)(ch * 8 + h) * 128 + b];
    }
    int idx = b * 256 + h * 32 + d;
    OMID[idx] = G[idx] * (o / l);
}

// ============================ round-0 attention (fallback) ====================
__global__ __launch_bounds__(256) void attn_kernel(
    const float* __restrict__ WQ, const float* __restrict__ WK, const float* __restrict__ WV,
    const float* __restrict__ G, float* __restrict__ OMID)
{
    __shared__ float red[4][64][33];
    const int h = blockIdx.y;
    const int bl = threadIdx.x >> 6;
    const int lane = threadIdx.x & 63;
    const int b = blockIdx.x * 4 + bl;
    float q[32];
    {
        const float* wq = &WQ[(size_t)b * 256 + h * 32];
#pragma unroll
        for (int j = 0; j < 8; ++j) {
            float4 v = *(const float4*)&wq[j * 4];
            q[j * 4 + 0] = v.x; q[j * 4 + 1] = v.y; q[j * 4 + 2] = v.z; q[j * 4 + 3] = v.w;
        }
    }
    float o[32];
#pragma unroll
    for (int d = 0; d < 32; ++d) o[d] = 0.f;
    float l = 0.f;
#pragma unroll 2
    for (int s = lane; s < 8192; s += 64) {
        const float* kr = &WK[(size_t)s * 256 + h * 32];
        float s0 = 0, s1 = 0, s2 = 0, s3 = 0;
#pragma unroll
        for (int j = 0; j < 8; ++j) {
            float4 kv = *(const float4*)&kr[j * 4];
            s0 = fmaf(q[j * 4 + 0], kv.x, s0);
            s1 = fmaf(q[j * 4 + 1], kv.y, s1);
            s2 = fmaf(q[j * 4 + 2], kv.z, s2);
            s3 = fmaf(q[j * 4 + 3], kv.w, s3);
        }
        float e = __expf((s0 + s1) + (s2 + s3) - 16.0f);
        l += e;
        const float* vr = &WV[(size_t)s * 256 + h * 32];
#pragma unroll
        for (int j = 0; j < 8; ++j) {
            float4 vv = *(const float4*)&vr[j * 4];
            o[j * 4 + 0] = fmaf(e, vv.x, o[j * 4 + 0]);
            o[j * 4 + 1] = fmaf(e, vv.y, o[j * 4 + 1]);
            o[j * 4 + 2] = fmaf(e, vv.z, o[j * 4 + 2]);
            o[j * 4 + 3] = fmaf(e, vv.w, o[j * 4 + 3]);
        }
    }
#pragma unroll
    for (int d = 0; d < 32; ++d) red[bl][lane][d] = o[d];
    red[bl][lane][32] = l;
    __syncthreads();
    if (threadIdx.x < 128) {
        int bl2 = threadIdx.x >> 5;
        int d = threadIdx.x & 31;
        float os = 0.f, ls = 0.f;
#pragma unroll 8
        for (int ln = 0; ln < 64; ++ln) {
            os += red[bl2][ln][d];
            ls += red[bl2][ln][32];
        }
        int b2 = blockIdx.x * 4 + bl2;
        int idx = b2 * 256 + h * 32 + d;
        OMID[idx] = G[idx] * (os / ls);
    }
}

extern "C" void kernel_launch(void* const* d_in, const int* in_sizes, int n_in,
                              void* d_out, int out_size, void* d_ws, size_t ws_size,
                              hipStream_t stream) {
    const float* q    = (const float*)d_in[0];
    const float* k    = (const float*)d_in[1];
    const float* v    = (const float*)d_in[2];
    const float* q_sw = (const float*)d_in[3];
    const float* q_bw = (const float*)d_in[4];
    const float* q_bb = (const float*)d_in[5];
    const float* k_sw = (const float*)d_in[6];
    const float* k_bw = (const float*)d_in[7];
    const float* k_bb = (const float*)d_in[8];
    const float* v_sw = (const float*)d_in[9];
    const float* v_bw = (const float*)d_in[10];
    const float* v_bb = (const float*)d_in[11];
    const float* g_sw = (const float*)d_in[12];
    const float* g_bw = (const float*)d_in[13];
    const float* g_bb = (const float*)d_in[14];
    const float* o_sw = (const float*)d_in[15];
    const float* o_bw = (const float*)d_in[16];
    const float* o_bb = (const float*)d_in[17];

    float* ws = (float*)d_ws;
    float* wk = ws;                         // 8192*256 (fallback fp32)
    float* wv = ws + 2097152;               // 8192*256 (fallback fp32)
    float* wq = ws + 4194304;               // 128*256 (fallback fp32)
    float* gb = ws + 4227072;               // 128*256 (fallback)
    float* om = ws + 4259840;               // 128*256
    short* Bk = (short*)(ws + 4292608);     // 256*2304 bf16
    short* Bv = (short*)(ws + 4587520);     // 256*2304 bf16
    float* Opart = ws + 4882432;            // 128*8*128*32
    float* Lpart = ws + 9076736;            // 128*8*128
    float* PART = Opart;                    // aliased, disjoint lifetime
    short* A0 = (short*)(ws + 9207808);     // 8192*2304 bf16
    short* A1 = (short*)(ws + 18644992);    // 8192*2304 bf16
    short* GPk = (short*)(ws + 28082176);   // 4 x 8192*256 bf16 quarter-partials
    short* GPv = (short*)(ws + 32276480);   // 4 x 8192*256 bf16
    short* Bq  = (short*)(ws + 36470784);   // 256*2304 bf16
    short* Bg  = (short*)(ws + 36765696);   // 256*2304 bf16
    short* Aq  = (short*)(ws + 37060608);   // 128*2304 bf16
    short* GPq = (short*)(ws + 37208064);   // 4 x 128*256 bf16
    short* GPg = (short*)(ws + 37273600);   // 4 x 128*256 bf16
    short* WQb = (short*)(ws + 37339136);   // 128*256 bf16 (fallback)
    short* Abuf = (short*)Opart;            // fallback aliased A
    float* out = (float*)d_out;

    const bool can_mfma   = ws_size >= (size_t)4882432 * 4;
    const bool can_bigger = ws_size >= (size_t)(4882432 + 9437184) * 4;
    const bool can_huge   = ws_size >= (size_t)37355520 * 4;   // ~149.4 MB

    dim3 blk(256);
    if (can_huge) {
        prep_basis<<<dim3(17088), blk, 0, stream>>>(
            k, v, q, A0, A1, Aq,
            k_sw, k_bw, Bk, v_sw, v_bw, Bv,
            q_sw, q_bw, Bq, g_sw, g_bw, Bg);
        stage2<<<dim3(1040), blk, 0, stream>>>(
            A0, A1, Aq, Bk, Bv, Bq, Bg, k_bb, v_bb, q_bb, g_bb,
            GPk, GPv, GPq, GPg);
        attn_mfma<<<dim3(128, 8), blk, 0, stream>>>(GPq, GPk, GPv, Opart, Lpart);
        attn_reduce2<<<dim3(128, 8), blk, 0, stream>>>(Opart, Lpart, GPg, om);
        fastkan_splitk<<<dim3(8, 9, 1), blk, 0, stream>>>(om, o_sw, o_bw, o_sw, o_bw, PART);
        reduce_kernel<0><<<dim3(128), blk, 0, stream>>>(PART, o_bb, out);
    } else if (can_bigger) {
        prep_kernel<<<dim3(36, 4, 2), blk, 0, stream>>>(k_sw, k_bw, Bk, v_sw, v_bw, Bv);
        fastkan_splitk<<<dim3(8, 9, 2), blk, 0, stream>>>(q, q_sw, q_bw, g_sw, g_bw, PART);
        reduce_qg<0><<<dim3(128, 2), blk, 0, stream>>>(PART, q_bb, g_bb, wq, gb, WQb);
        basis_gen2<<<dim3(8192, 1), blk, 0, stream>>>(k, k, Abuf, Abuf);
        gemm_tile<<<dim3(128, 4), blk, 0, stream>>>(Abuf, Bk, k_bb, wk);
        basis_gen2<<<dim3(8192, 1), blk, 0, stream>>>(v, v, Abuf, Abuf);
        gemm_tile<<<dim3(128, 4), blk, 0, stream>>>(Abuf, Bv, v_bb, wv);
        attn_chunk<<<dim3(128, 8), blk, 0, stream>>>(wq, wk, wv, Opart, Lpart);
        attn_reduce<<<dim3(128), blk, 0, stream>>>(Opart, Lpart, gb, om);
        fastkan_splitk<<<dim3(8, 9, 1), blk, 0, stream>>>(om, o_sw, o_bw, o_sw, o_bw, PART);
        reduce_kernel<0><<<dim3(128), blk, 0, stream>>>(PART, o_bb, out);
    } else {
        fastkan_kernel<64, 64, 0><<<dim3(128, 4), blk, 0, stream>>>(k, k_sw, k_bw, k_bb, wk);
        fastkan_kernel<64, 64, 0><<<dim3(128, 4), blk, 0, stream>>>(v, v_sw, v_bw, v_bb, wv);
        fastkan_kernel<32, 32, 1><<<dim3(4, 8), blk, 0, stream>>>(q, q_sw, q_bw, q_bb, wq);
        fastkan_kernel<32, 32, 2><<<dim3(4, 8), blk, 0, stream>>>(q, g_sw, g_bw, g_bb, gb);
        attn_kernel<<<dim3(32, 8), blk, 0, stream>>>(wq, wk, wv, gb, om);
        fastkan_kernel<32, 32, 0><<<dim3(4, 8), blk, 0, stream>>>(om, o_sw, o_bw, o_bb, out);
    }
}

// Round 19
// 99.118 us; speedup vs baseline: 1.0271x; 1.0271x over previous
//
#include <hip/hip_runtime.h>
#include <math.h>

#define IN_DIM 256
#define OUT_DIM 256

typedef short short8 __attribute__((ext_vector_type(8)));
typedef short short4_t __attribute__((ext_vector_type(4)));
typedef float f32x4 __attribute__((ext_vector_type(4)));
typedef unsigned int u32;

static __device__ __forceinline__ short f2bf(float f) {
    union { float f; unsigned u; } c; c.f = f;
    unsigned r = (c.u + 0x7FFFu + ((c.u >> 16) & 1u)) >> 16;
    return (short)r;
}
static __device__ __forceinline__ float bf2f(short s) {
    union { unsigned u; float f; } c;
    c.u = ((u32)(unsigned short)s) << 16;
    return c.f;
}

// async global->LDS, 16B per lane. LDS dest must be linear in lane (base + lane*16).
static __device__ __forceinline__ void gload16(const void* g, void* l) {
    __builtin_amdgcn_global_load_lds(
        (const __attribute__((address_space(1))) u32*)g,
        (__attribute__((address_space(3))) u32*)l, 16, 0, 0);
}

// ============================ round-0 fp32 fastkan (fallback only) ============
template<int RT, int CT, int MODE>
__global__ __launch_bounds__(256) void fastkan_kernel(
    const float* __restrict__ X, const float* __restrict__ SW,
    const float* __restrict__ BW, const float* __restrict__ BB,
    float* __restrict__ OUT)
{
    constexpr int TRT = RT / 16;
    constexpr int TCT = CT / 16;
    __shared__ float aT[64][RT];
    __shared__ float bT[64][CT];
    const int t = threadIdx.x, tr = t >> 4, tc = t & 15;
    const int r0 = blockIdx.x * RT, c0 = blockIdx.y * CT;
    float acc[TRT][TCT];
#pragma unroll
    for (int a = 0; a < TRT; ++a)
#pragma unroll
        for (int b = 0; b < TCT; ++b) acc[a][b] = 0.f;

    for (int i0 = 0; i0 < IN_DIM; i0 += 8) {
        __syncthreads();
        constexpr int PER_A = (RT * 8) / 256;
#pragma unroll
        for (int j = 0; j < PER_A; ++j) {
            int p = j * 256 + t;
            int i = p & 7, r = p >> 3;
            float x = X[(size_t)(r0 + r) * IN_DIM + (i0 + i)];
#pragma unroll
            for (int g = 0; g < 8; ++g) {
                float z = (x - (-2.0f + (float)g * (4.0f / 7.0f))) * 1.75f;
                aT[i * 8 + g][r] = __expf(-z * z);
            }
        }
#pragma unroll
        for (int j = 0; j < (64 * CT) / 1024; ++j) {
            int p = j * 256 + t;
            int c4 = p % (CT / 4), kk = p / (CT / 4);
            *(float4*)&bT[kk][c4 * 4] =
                *(const float4*)&SW[(size_t)(i0 * 8 + kk) * OUT_DIM + (c0 + c4 * 4)];
        }
        __syncthreads();
#pragma unroll 8
        for (int kk = 0; kk < 64; ++kk) {
            float av[TRT], bv[TCT];
#pragma unroll
            for (int a = 0; a < TRT; ++a) av[a] = aT[kk][tr * TRT + a];
#pragma unroll
            for (int b = 0; b < TCT; ++b) bv[b] = bT[kk][tc * TCT + b];
#pragma unroll
            for (int a = 0; a < TRT; ++a)
#pragma unroll
                for (int b = 0; b < TCT; ++b)
                    acc[a][b] = fmaf(av[a], bv[b], acc[a][b]);
        }
    }
    for (int i0 = 0; i0 < IN_DIM; i0 += 64) {
        __syncthreads();
#pragma unroll
        for (int j = 0; j < (RT * 64) / 1024; ++j) {
            int p = j * 256 + t;
            int i4 = p & 15, r = p >> 4;
            float4 xv = *(const float4*)&X[(size_t)(r0 + r) * IN_DIM + (i0 + i4 * 4)];
            const float* xe = &xv.x;
#pragma unroll
            for (int e = 0; e < 4; ++e) {
                float x = xe[e];
                aT[i4 * 4 + e][r] = x / (1.f + __expf(-x));
            }
        }
#pragma unroll
        for (int j = 0; j < (64 * CT) / 1024; ++j) {
            int p = j * 256 + t;
            int c4 = p % (CT / 4), kk = p / (CT / 4);
            *(float4*)&bT[kk][c4 * 4] =
                *(const float4*)&BW[(size_t)(i0 + kk) * OUT_DIM + (c0 + c4 * 4)];
        }
        __syncthreads();
#pragma unroll 8
        for (int kk = 0; kk < 64; ++kk) {
            float av[TRT], bv[TCT];
#pragma unroll
            for (int a = 0; a < TRT; ++a) av[a] = aT[kk][tr * TRT + a];
#pragma unroll
            for (int b = 0; b < TCT; ++b) bv[b] = bT[kk][tc * TCT + b];
#pragma unroll
            for (int a = 0; a < TRT; ++a)
#pragma unroll
                for (int b = 0; b < TCT; ++b)
                    acc[a][b] = fmaf(av[a], bv[b], acc[a][b]);
        }
    }
#pragma unroll
    for (int a = 0; a < TRT; ++a) {
        int r = r0 + tr * TRT + a;
#pragma unroll
        for (int b = 0; b < TCT; ++b) {
            int c = c0 + tc * TCT + b;
            float v = acc[a][b] + BB[c];
            if (MODE == 1) v *= 0.17677669529663687f;
            if (MODE == 2) v = 1.f / (1.f + __expf(-v));
            OUT[(size_t)r * OUT_DIM + c] = v;
        }
    }
}

// ============================ split-K fastkan (o-layer + fallback q/g) ========
__global__ __launch_bounds__(256) void fastkan_splitk(
    const float* __restrict__ X,
    const float* __restrict__ SW0, const float* __restrict__ BW0,
    const float* __restrict__ SW1, const float* __restrict__ BW1,
    float* __restrict__ PART)
{
    __shared__ float aT[128][65];
    __shared__ float bT[64][33];

    const int t = threadIdx.x;
    const int tr = t >> 4, tc = t & 15;
    const int c0 = blockIdx.x * 32;
    const int kc = blockIdx.y;
    const int z = blockIdx.z;
    const float* SW = z ? SW1 : SW0;
    const float* BW = z ? BW1 : BW0;

    float acc[8][2];
#pragma unroll
    for (int a = 0; a < 8; ++a) { acc[a][0] = 0.f; acc[a][1] = 0.f; }

    for (int sub = 0; sub < 4; ++sub) {
        const int k0 = kc * 256 + sub * 64;
        __syncthreads();
        if (kc < 8) {
            const int i0 = kc * 32 + sub * 8;
#pragma unroll
            for (int it = 0; it < 4; ++it) {
                int p = it * 256 + t;
                int row = p & 127, i = p >> 7;
                float x = X[(size_t)row * 256 + i0 + i];
#pragma unroll
                for (int g = 0; g < 8; ++g) {
                    float zz = (x - (-2.0f + (float)g * (4.0f / 7.0f))) * 1.75f;
                    aT[row][i * 8 + g] = __expf(-zz * zz);
                }
            }
        } else {
            const int f0 = sub * 64;
            int row = t >> 1, seg = t & 1;
            const float* xr = &X[(size_t)row * 256 + f0 + seg * 32];
#pragma unroll
            for (int j4 = 0; j4 < 8; ++j4) {
                float4 xv = *(const float4*)&xr[j4 * 4];
                const float* xe = &xv.x;
#pragma unroll
                for (int e = 0; e < 4; ++e) {
                    float x = xe[e];
                    aT[row][seg * 32 + j4 * 4 + e] = x / (1.f + __expf(-x));
                }
            }
        }
        {
            const float* Wsrc = (kc < 8) ? &SW[(size_t)k0 * 256] : &BW[(size_t)(k0 - 2048) * 256];
#pragma unroll
            for (int it = 0; it < 2; ++it) {
                int p = it * 256 + t;
                int kk = p >> 3, c4 = p & 7;
                float4 v = *(const float4*)&Wsrc[(size_t)kk * 256 + c0 + c4 * 4];
                bT[kk][c4 * 4 + 0] = v.x; bT[kk][c4 * 4 + 1] = v.y;
                bT[kk][c4 * 4 + 2] = v.z; bT[kk][c4 * 4 + 3] = v.w;
            }
        }
        __syncthreads();
#pragma unroll 8
        for (int kk = 0; kk < 64; ++kk) {
            float av[8], bv[2];
#pragma unroll
            for (int a = 0; a < 8; ++a) av[a] = aT[tr * 8 + a][kk];
            bv[0] = bT[kk][tc * 2 + 0];
            bv[1] = bT[kk][tc * 2 + 1];
#pragma unroll
            for (int a = 0; a < 8; ++a) {
                acc[a][0] = fmaf(av[a], bv[0], acc[a][0]);
                acc[a][1] = fmaf(av[a], bv[1], acc[a][1]);
            }
        }
    }
#pragma unroll
    for (int a = 0; a < 8; ++a) {
        int r = tr * 8 + a;
        float* dst = &PART[((size_t)(z * 9 + kc) * 128 + r) * 256 + c0 + tc * 2];
        dst[0] = acc[a][0];
        dst[1] = acc[a][1];
    }
}

template<int MODE>
__global__ __launch_bounds__(256) void reduce_kernel(
    const float* __restrict__ PART, const float* __restrict__ BB, float* __restrict__ OUT)
{
    const int r = blockIdx.x, t = threadIdx.x;
    float s = 0.f;
#pragma unroll
    for (int kc = 0; kc < 9; ++kc)
        s += PART[((size_t)kc * 128 + r) * 256 + t];
    float v = s + BB[t];
    if (MODE == 1) v *= 0.17677669529663687f;
    if (MODE == 2) v = 1.f / (1.f + __expf(-v));
    OUT[(size_t)r * 256 + t] = v;
}

// fallback q/g reduce
template<int WB>
__global__ __launch_bounds__(256) void reduce_qg(
    const float* __restrict__ PART, const float* __restrict__ QBB,
    const float* __restrict__ GBB, float* __restrict__ WQ, float* __restrict__ GB,
    short* __restrict__ WQb)
{
    const int r = blockIdx.x, t = threadIdx.x, z = blockIdx.y;
    const float* P = PART + (size_t)z * 9 * 128 * 256;
    float s = 0.f;
#pragma unroll
    for (int kc = 0; kc < 9; ++kc)
        s += P[((size_t)kc * 128 + r) * 256 + t];
    if (z == 0) {
        float v = (s + QBB[t]) * 0.17677669529663687f;
        WQ[(size_t)r * 256 + t] = v;
        if (WB) WQb[(size_t)r * 256 + t] = f2bf(v);
    } else {
        float v = s + GBB[t];
        GB[(size_t)r * 256 + t] = 1.f / (1.f + __expf(-v));
    }
}

// ============================ weight prep (fallback standalone) ===============
__global__ __launch_bounds__(256) void prep_kernel(
    const float* __restrict__ SWk, const float* __restrict__ BWk, short* __restrict__ Bk,
    const float* __restrict__ SWv, const float* __restrict__ BWv, short* __restrict__ Bv)
{
    __shared__ float tile[64][65];
    const int t = threadIdx.x;
    const int kk0 = blockIdx.x * 64;
    const int c0 = blockIdx.y * 64;
    const float* SW = blockIdx.z ? SWv : SWk;
    const float* BW = blockIdx.z ? BWv : BWk;
    short* Bdst = blockIdx.z ? Bv : Bk;

#pragma unroll
    for (int j = 0; j < 4; ++j) {
        int p = j * 256 + t;
        int lr = p >> 4, lc4 = p & 15;
        float4 v;
        if (kk0 < 2048) v = *(const float4*)&SW[(size_t)(kk0 + lr) * 256 + c0 + lc4 * 4];
        else            v = *(const float4*)&BW[(size_t)(kk0 - 2048 + lr) * 256 + c0 + lc4 * 4];
        tile[lr][lc4 * 4 + 0] = v.x; tile[lr][lc4 * 4 + 1] = v.y;
        tile[lr][lc4 * 4 + 2] = v.z; tile[lr][lc4 * 4 + 3] = v.w;
    }
    __syncthreads();
#pragma unroll
    for (int j = 0; j < 4; ++j) {
        int p = j * 256 + t;
        int lc = p >> 4, lk4 = p & 15;
        short4_t s;
#pragma unroll
        for (int e = 0; e < 4; ++e) s[e] = f2bf(tile[lk4 * 4 + e][lc]);
        *(short4_t*)&Bdst[(size_t)(c0 + lc) * 2304 + kk0 + lk4 * 4] = s;
    }
}

// ============================ basis precompute (fallback standalone) ==========
__global__ __launch_bounds__(256) void basis_gen2(
    const float* __restrict__ K, const float* __restrict__ V,
    short* __restrict__ A0, short* __restrict__ A1)
{
    const float* X = blockIdx.y ? V : K;
    short* A = blockIdx.y ? A1 : A0;
    const int row = blockIdx.x;
    const int t = threadIdx.x;
    float x = X[(size_t)row * 256 + t];
    short8 s;
#pragma unroll
    for (int g = 0; g < 8; ++g) {
        float z = (x - (-2.0f + (float)g * (4.0f / 7.0f))) * 1.75f;
        s[g] = f2bf(__expf(-z * z));
    }
    *(short8*)&A[(size_t)row * 2304 + t * 8] = s;
    if (t < 32) {
        const float* xr = &X[(size_t)row * 256 + t * 8];
        short8 sl;
#pragma unroll
        for (int e2 = 0; e2 < 2; ++e2) {
            float4 xv = *(const float4*)&xr[e2 * 4];
            const float* xe = &xv.x;
#pragma unroll
            for (int e = 0; e < 4; ++e) {
                float xx = xe[e];
                sl[e2 * 4 + e] = f2bf(xx / (1.f + __expf(-xx)));
            }
        }
        *(short8*)&A[(size_t)row * 2304 + 2048 + t * 8] = sl;
    }
}

// ============================ fused prep + basis (k,v,q basis; k,v,q,g weights)
// bid < 16512: basis rows. m = bid>>13 (0=k rows 0..8191, 1=v, 2=q rows 0..127)
// bid >= 16512: weight-transpose tiles, 144 per matrix, order k,v,q,g
__global__ __launch_bounds__(256) void prep_basis(
    const float* __restrict__ K, const float* __restrict__ V, const float* __restrict__ Q,
    short* __restrict__ A0, short* __restrict__ A1, short* __restrict__ Aq,
    const float* __restrict__ SWk, const float* __restrict__ BWk, short* __restrict__ Bk,
    const float* __restrict__ SWv, const float* __restrict__ BWv, short* __restrict__ Bv,
    const float* __restrict__ SWq, const float* __restrict__ BWq, short* __restrict__ Bq,
    const float* __restrict__ SWg, const float* __restrict__ BWg, short* __restrict__ Bg)
{
    __shared__ float tile[64][65];
    const int bid = blockIdx.x;
    const int t = threadIdx.x;
    if (bid < 16512) {
        const int m = bid >> 13;
        const float* X = (m == 0) ? K : ((m == 1) ? V : Q);
        short* A = (m == 0) ? A0 : ((m == 1) ? A1 : Aq);
        const int row = bid & 8191;
        float x = X[(size_t)row * 256 + t];
        short8 s;
#pragma unroll
        for (int g = 0; g < 8; ++g) {
            float z = (x - (-2.0f + (float)g * (4.0f / 7.0f))) * 1.75f;
            s[g] = f2bf(__expf(-z * z));
        }
        *(short8*)&A[(size_t)row * 2304 + t * 8] = s;
        if (t < 32) {
            const float* xr = &X[(size_t)row * 256 + t * 8];
            short8 sl;
#pragma unroll
            for (int e2 = 0; e2 < 2; ++e2) {
                float4 xv = *(const float4*)&xr[e2 * 4];
                const float* xe = &xv.x;
#pragma unroll
                for (int e = 0; e < 4; ++e) {
                    float xx = xe[e];
                    sl[e2 * 4 + e] = f2bf(xx / (1.f + __expf(-xx)));
                }
            }
            *(short8*)&A[(size_t)row * 2304 + 2048 + t * 8] = sl;
        }
        return;
    }
    const int p = bid - 16512;
    const int mat = p / 144;
    const int q = p % 144;
    const int kk0 = (q >> 2) * 64;
    const int c0 = (q & 3) * 64;
    const float* SW = (mat == 0) ? SWk : ((mat == 1) ? SWv : ((mat == 2) ? SWq : SWg));
    const float* BW = (mat == 0) ? BWk : ((mat == 1) ? BWv : ((mat == 2) ? BWq : BWg));
    short* Bdst     = (mat == 0) ? Bk  : ((mat == 1) ? Bv  : ((mat == 2) ? Bq  : Bg));

#pragma unroll
    for (int j = 0; j < 4; ++j) {
        int pp = j * 256 + t;
        int lr = pp >> 4, lc4 = pp & 15;
        float4 v;
        if (kk0 < 2048) v = *(const float4*)&SW[(size_t)(kk0 + lr) * 256 + c0 + lc4 * 4];
        else            v = *(const float4*)&BW[(size_t)(kk0 - 2048 + lr) * 256 + c0 + lc4 * 4];
        tile[lr][lc4 * 4 + 0] = v.x; tile[lr][lc4 * 4 + 1] = v.y;
        tile[lr][lc4 * 4 + 2] = v.z; tile[lr][lc4 * 4 + 3] = v.w;
    }
    __syncthreads();
#pragma unroll
    for (int j = 0; j < 4; ++j) {
        int pp = j * 256 + t;
        int lc = pp >> 4, lk4 = pp & 15;
        short4_t s;
#pragma unroll
        for (int e = 0; e < 4; ++e) s[e] = f2bf(tile[lk4 * 4 + e][lc]);
        *(short4_t*)&Bdst[(size_t)(c0 + lc) * 2304 + kk0 + lk4 * 4] = s;
    }
}

// ============================ STAGE 2: uniform 18-step split-K gemm ===========
// bid < 512 : kv gemm (x=bid&63, y=(bid>>6)&1, z=bid>>7 = mat*2+kh)
// bid >= 512: q/g gemm (p=bid-512: layer=p>>2 (0=q,1=g), y=(p>>1)&1, kh=p&1; r0=0)
// All blocks: 18 K-steps, 128x128 tile, bf16 half-partials; kh=0 carries bias
// (and, for q, both halves carry the 1/sqrt(32) scale).
__global__ __launch_bounds__(256) void stage2(
    const short* __restrict__ A0, const short* __restrict__ A1, const short* __restrict__ Aq,
    const short* __restrict__ Bk, const short* __restrict__ Bv,
    const short* __restrict__ Bq, const short* __restrict__ Bg,
    const float* __restrict__ BBk, const float* __restrict__ BBv,
    const float* __restrict__ QBB, const float* __restrict__ GBB,
    short* __restrict__ GPk0, short* __restrict__ GPk1,
    short* __restrict__ GPv0, short* __restrict__ GPv1,
    short* __restrict__ GPq0, short* __restrict__ GPq1,
    short* __restrict__ GPg0, short* __restrict__ GPg1)
{
    __shared__ __align__(16) short Al[128 * 64];
    __shared__ __align__(16) short Bl[128 * 64];

    const int bid = blockIdx.x;
    const int t = threadIdx.x;
    const int lane = t & 63, wid = t >> 6;
    const int wm = wid >> 1, wn = wid & 1;
    const int lrow = lane & 15;
    const int lkb = (lane >> 4) * 16;

    // uniform geometry; only base pointers/epilogue vary
    const short* A;
    const short* B2;
    int r0, c0, kh, which;            // which: 0=k 1=v 2=q 3=g
    if (bid < 512) {
        const int z = bid >> 7;
        which = (z >> 1);             // 0 or 1
        kh = z & 1;
        A  = which ? A1 : A0;
        B2 = which ? Bv : Bk;
        r0 = (bid & 63) * 128;
        c0 = ((bid >> 6) & 1) * 128;
    } else {
        const int p = bid - 512;
        which = 2 + (p >> 2);         // 2 or 3
        kh = p & 1;
        A = Aq;
        B2 = (which == 3) ? Bg : Bq;
        r0 = 0;
        c0 = ((p >> 1) & 1) * 128;
    }
    const int kbase = kh * 1152;

    f32x4 acc[4][4];
#pragma unroll
    for (int a = 0; a < 4; ++a)
#pragma unroll
        for (int c = 0; c < 4; ++c) acc[a][c] = (f32x4){0.f, 0.f, 0.f, 0.f};

    for (int st = 0; st < 18; ++st) {
        const int k0 = kbase + st * 64;
        __syncthreads();
#pragma unroll
        for (int i = 0; i < 4; ++i) {
            int f = i * 256 + t;
            int row = f >> 3, kg = f & 7;
            gload16(&A[(size_t)(r0 + row) * 2304 + k0 + kg * 8], (char*)Al + f * 16);
        }
#pragma unroll
        for (int i = 0; i < 4; ++i) {
            int f = i * 256 + t;
            int c = f >> 3, kg = f & 7;
            gload16(&B2[(size_t)(c0 + c) * 2304 + k0 + kg * 8], (char*)Bl + f * 16);
        }
        __syncthreads();
#pragma unroll
        for (int kf = 0; kf < 2; ++kf) {
            short8 af[4], bf[4];
#pragma unroll
            for (int a = 0; a < 4; ++a) {
                int R = wm * 64 + a * 16 + lrow;
                af[a] = *(short8*)((char*)Al + R * 128 + kf * 64 + lkb);
            }
#pragma unroll
            for (int c = 0; c < 4; ++c) {
                int C = wn * 64 + c * 16 + lrow;
                bf[c] = *(short8*)((char*)Bl + C * 128 + kf * 64 + lkb);
            }
#pragma unroll
            for (int a = 0; a < 4; ++a)
#pragma unroll
                for (int c = 0; c < 4; ++c)
                    acc[a][c] = __builtin_amdgcn_mfma_f32_16x16x32_bf16(af[a], bf[c], acc[a][c], 0, 0, 0);
        }
    }

    short* OUT;
    const float* BB;
    float scale = 1.0f;
    if (which == 0)      { OUT = kh ? GPk1 : GPk0; BB = BBk; }
    else if (which == 1) { OUT = kh ? GPv1 : GPv0; BB = BBv; }
    else if (which == 2) { OUT = kh ? GPq1 : GPq0; BB = QBB; scale = 0.17677669529663687f; }
    else                 { OUT = kh ? GPg1 : GPg0; BB = GBB; }

#pragma unroll
    for (int a = 0; a < 4; ++a)
#pragma unroll
        for (int c = 0; c < 4; ++c) {
            int col = c0 + wn * 64 + c * 16 + lrow;
            float bias = (kh == 0) ? BB[col] : 0.f;
#pragma unroll
            for (int j = 0; j < 4; ++j) {
                int row = r0 + wm * 64 + a * 16 + (lane >> 4) * 4 + j;
                OUT[(size_t)row * 256 + col] = f2bf((acc[a][c][j] + bias) * scale);
            }
        }
}

// ============================ 64-tile GEMM (fallback, reg-staged, fp32 out) ===
__global__ __launch_bounds__(256) void gemm_tile(
    const short* __restrict__ A, const short* __restrict__ B2,
    const float* __restrict__ BB, float* __restrict__ OUT)
{
    __shared__ __align__(16) short A_l[64 * 64];
    __shared__ __align__(16) short B_l[64 * 64];
    char* ab = (char*)A_l;
    char* bb = (char*)B_l;

    const int t = threadIdx.x;
    const int r0 = blockIdx.x * 64;
    const int c0 = blockIdx.y * 64;
    const int lane = t & 63;
    const int wid = t >> 6;
    const int wm = wid >> 1, wn = wid & 1;
    const int lrow = lane & 15;
    const int lkb = (lane >> 4) * 16;

    f32x4 acc[2][2];
#pragma unroll
    for (int a = 0; a < 2; ++a)
#pragma unroll
        for (int c = 0; c < 2; ++c) acc[a][c] = (f32x4){0.f, 0.f, 0.f, 0.f};

    for (int st = 0; st < 36; ++st) {
        const int k0 = st * 64;
        __syncthreads();
#pragma unroll
        for (int it = 0; it < 2; ++it) {
            int p = it * 256 + t;
            int row = p >> 3, kg = p & 7;
            short8 s = *(const short8*)&A[(size_t)(r0 + row) * 2304 + k0 + kg * 8];
            int off = (row * 128 + kg * 16) ^ ((row & 7) << 4);
            *(short8*)(ab + off) = s;
        }
#pragma unroll
        for (int it = 0; it < 2; ++it) {
            int p = it * 256 + t;
            int c = p >> 3, kg = p & 7;
            short8 s = *(const short8*)&B2[(size_t)(c0 + c) * 2304 + k0 + kg * 8];
            int off = (c * 128 + kg * 16) ^ ((c & 7) << 4);
            *(short8*)(bb + off) = s;
        }
        __syncthreads();
#pragma unroll
        for (int kf = 0; kf < 2; ++kf) {
            short8 af[2], bf[2];
#pragma unroll
            for (int a = 0; a < 2; ++a) {
                int R = wm * 32 + a * 16 + lrow;
                int off = (R * 128 + kf * 64 + lkb) ^ ((R & 7) << 4);
                af[a] = *(short8*)(ab + off);
            }
#pragma unroll
            for (int c = 0; c < 2; ++c) {
                int R = wn * 32 + c * 16 + lrow;
                int off = (R * 128 + kf * 64 + lkb) ^ ((R & 7) << 4);
                bf[c] = *(short8*)(bb + off);
            }
#pragma unroll
            for (int a = 0; a < 2; ++a)
#pragma unroll
                for (int c = 0; c < 2; ++c)
                    acc[a][c] = __builtin_amdgcn_mfma_f32_16x16x32_bf16(af[a], bf[c], acc[a][c], 0, 0, 0);
        }
    }
#pragma unroll
    for (int a = 0; a < 2; ++a)
#pragma unroll
        for (int c = 0; c < 2; ++c) {
            int col = c0 + wn * 32 + c * 16 + (lane & 15);
            float bias = BB[col];
#pragma unroll
            for (int j = 0; j < 4; ++j) {
                int row = r0 + wm * 32 + a * 16 + (lane >> 4) * 4 + j;
                OUT[(size_t)row * 256 + col] = acc[a][c][j] + bias;
            }
        }
}

// ============================ MFMA attention (halves-summed Q/K/V staging) ====
__global__ __launch_bounds__(256) void attn_mfma(
    const short* __restrict__ Q0, const short* __restrict__ Q1,
    const short* __restrict__ K0, const short* __restrict__ K1,
    const short* __restrict__ V0, const short* __restrict__ V1,
    float* __restrict__ OPART, float* __restrict__ LPART)
{
    __shared__ __align__(16) short Ql[128 * 32];   // [q][d] linear
    __shared__ __align__(16) short Kl[64 * 32];    // [s][d] linear
    __shared__ __align__(16) short Vt[32 * 64];    // [d][s] swizzled
    __shared__ __align__(16) short El[128 * 64];   // [q][s] swizzled
    char* ql = (char*)Ql; char* kl = (char*)Kl;
    char* vt = (char*)Vt; char* el = (char*)El;

    const int t = threadIdx.x, lane = t & 63, w = t >> 6;
    const int ch = blockIdx.x, h = blockIdx.y, s0 = ch * 64;
    const int lr = lane & 15, lg = lane >> 4;

    {
        // Q = Q0 + Q1 (scale & bias folded per-half)
#pragma unroll
        for (int i = 0; i < 2; ++i) {
            int f = i * 256 + t;
            int row = f >> 2, d8 = (f & 3) * 8;
            size_t qoff = (size_t)row * 256 + h * 32 + d8;
            short8 qa = *(const short8*)&Q0[qoff];
            short8 qb = *(const short8*)&Q1[qoff];
            short8 qs;
#pragma unroll
            for (int e = 0; e < 8; ++e) qs[e] = f2bf(bf2f(qa[e]) + bf2f(qb[e]));
            *(short8*)(ql + f * 16) = qs;
        }
        int s = t >> 2, d8 = (t & 3) * 8;
        size_t off = (size_t)(s0 + s) * 256 + h * 32 + d8;
        short8 ka = *(const short8*)&K0[off];
        short8 kb = *(const short8*)&K1[off];
        short8 ks;
#pragma unroll
        for (int e = 0; e < 8; ++e) ks[e] = f2bf(bf2f(ka[e]) + bf2f(kb[e]));
        *(short8*)(kl + t * 16) = ks;
        short8 va = *(const short8*)&V0[off];
        short8 vb = *(const short8*)&V1[off];
#pragma unroll
        for (int e = 0; e < 8; ++e) {
            int d = d8 + e;
            *(short*)(vt + ((d * 128 + s * 2) ^ ((d & 7) << 4))) = f2bf(bf2f(va[e]) + bf2f(vb[e]));
        }
    }
    __syncthreads();

#pragma unroll
    for (int i = 0; i < 2; ++i) {
        const int q = (w * 2 + i) * 16 + lr;
        short8 bq = *(short8*)(ql + q * 64 + lg * 16);
        float ls = 0.f;
#pragma unroll
        for (int j = 0; j < 4; ++j) {
            short8 ak = *(short8*)(kl + (j * 16 + lr) * 64 + lg * 16);
            f32x4 sc = {0.f, 0.f, 0.f, 0.f};
            sc = __builtin_amdgcn_mfma_f32_16x16x32_bf16(ak, bq, sc, 0, 0, 0);
            short4_t ep;
#pragma unroll
            for (int jj = 0; jj < 4; ++jj) {
                float e = __expf(sc[jj] - 16.0f);
                ls += e;
                ep[jj] = f2bf(e);
            }
            int sb = j * 16 + lg * 4;
            *(short4_t*)(el + ((q * 128 + sb * 2) ^ ((q & 7) << 4))) = ep;
        }
        ls += __shfl_xor(ls, 16);
        ls += __shfl_xor(ls, 32);
        if (lg == 0)
            LPART[(size_t)(ch * 8 + h) * 128 + (w * 2 + i) * 16 + lr] = ls;
    }
    __syncthreads();

    f32x4 oacc[2][2];
#pragma unroll
    for (int i = 0; i < 2; ++i)
#pragma unroll
        for (int d = 0; d < 2; ++d) oacc[i][d] = (f32x4){0.f, 0.f, 0.f, 0.f};
#pragma unroll
    for (int kf = 0; kf < 2; ++kf) {
        short8 ea[2], vb[2];
#pragma unroll
        for (int i = 0; i < 2; ++i) {
            int q = (w * 2 + i) * 16 + lr;
            ea[i] = *(short8*)(el + ((q * 128 + kf * 64 + lg * 16) ^ ((q & 7) << 4)));
        }
#pragma unroll
        for (int d = 0; d < 2; ++d) {
            int dd = d * 16 + lr;
            vb[d] = *(short8*)(vt + ((dd * 128 + kf * 64 + lg * 16) ^ ((dd & 7) << 4)));
        }
#pragma unroll
        for (int i = 0; i < 2; ++i)
#pragma unroll
            for (int d = 0; d < 2; ++d)
                oacc[i][d] = __builtin_amdgcn_mfma_f32_16x16x32_bf16(ea[i], vb[d], oacc[i][d], 0, 0, 0);
    }
#pragma unroll
    for (int i = 0; i < 2; ++i)
#pragma unroll
        for (int d = 0; d < 2; ++d) {
            int dd = d * 16 + lr;
#pragma unroll
            for (int j = 0; j < 4; ++j) {
                int q = (w * 2 + i) * 16 + lg * 4 + j;
                OPART[((size_t)(ch * 8 + h) * 128 + q) * 32 + dd] = oacc[i][d][j];
            }
        }
}

// ============================ parallel attention reduce (gate from g halves) ==
__global__ __launch_bounds__(256) void attn_reduce2(
    const float* __restrict__ OPART, const float* __restrict__ LPART,
    const short* __restrict__ G0, const short* __restrict__ G1,
    float* __restrict__ OMID)
{
    __shared__ float so[8][33];
    __shared__ float sl[8];
    const int b = blockIdx.x, h = blockIdx.y;
    const int t = threadIdx.x;
    const int d = t & 31, part = t >> 5;
    float o = 0.f, l = 0.f;
#pragma unroll 4
    for (int cc = 0; cc < 16; ++cc) {
        int ch = part * 16 + cc;
        o += OPART[((size_t)(ch * 8 + h) * 128 + b) * 32 + d];
        l += LPART[(size_t)(ch * 8 + h) * 128 + b];
    }
    so[part][d] = o;
    if (d == 0) sl[part] = l;
    __syncthreads();
    if (t < 32) {
        float oo = 0.f, ll = 0.f;
#pragma unroll
        for (int p = 0; p < 8; ++p) { oo += so[p][t]; ll += sl[p]; }
        int idx = b * 256 + h * 32 + t;
        float g = 1.f / (1.f + __expf(-(bf2f(G0[idx]) + bf2f(G1[idx]))));
        OMID[idx] = g * (oo / ll);
    }
}

// ============================ fp32 chunked attention (fallback) ===============
__global__ __launch_bounds__(256) void attn_chunk(
    const float* __restrict__ WQ, const float* __restrict__ WK, const float* __restrict__ WV,
    float* __restrict__ OPART, float* __restrict__ LPART)
{
    __shared__ float sWQ[128][33];
    __shared__ float sWK[64][33];
    __shared__ float sWV[64][33];
    __shared__ float sE[128][66];
    __shared__ float lred[128][16];

    const int t = threadIdx.x;
    const int ch = blockIdx.x;
    const int h = blockIdx.y;
    const int s0 = ch * 64;

    {
        int b = t >> 1, seg = t & 1;
        const float* src = &WQ[(size_t)b * 256 + h * 32 + seg * 16];
#pragma unroll
        for (int j = 0; j < 4; ++j) {
            float4 v = *(const float4*)&src[j * 4];
            sWQ[b][seg * 16 + j * 4 + 0] = v.x; sWQ[b][seg * 16 + j * 4 + 1] = v.y;
            sWQ[b][seg * 16 + j * 4 + 2] = v.z; sWQ[b][seg * 16 + j * 4 + 3] = v.w;
        }
        if (t < 128) {
            int s = t >> 1; seg = t & 1;
            const float* sk = &WK[(size_t)(s0 + s) * 256 + h * 32 + seg * 16];
#pragma unroll
            for (int j = 0; j < 4; ++j) {
                float4 v = *(const float4*)&sk[j * 4];
                sWK[s][seg * 16 + j * 4 + 0] = v.x; sWK[s][seg * 16 + j * 4 + 1] = v.y;
                sWK[s][seg * 16 + j * 4 + 2] = v.z; sWK[s][seg * 16 + j * 4 + 3] = v.w;
            }
        } else {
            int t2 = t - 128;
            int s = t2 >> 1; seg = t2 & 1;
            const float* sv = &WV[(size_t)(s0 + s) * 256 + h * 32 + seg * 16];
#pragma unroll
            for (int j = 0; j < 4; ++j) {
                float4 v = *(const float4*)&sv[j * 4];
                sWV[s][seg * 16 + j * 4 + 0] = v.x; sWV[s][seg * 16 + j * 4 + 1] = v.y;
                sWV[s][seg * 16 + j * 4 + 2] = v.z; sWV[s][seg * 16 + j * 4 + 3] = v.w;
            }
        }
    }
    __syncthreads();

    const int tr = t >> 4, tc = t & 15;
    {
        float acc[8][4];
#pragma unroll
        for (int a = 0; a < 8; ++a)
#pragma unroll
            for (int b = 0; b < 4; ++b) acc[a][b] = 0.f;
#pragma unroll 4
        for (int kk = 0; kk < 32; ++kk) {
            float av[8], bv[4];
#pragma unroll
            for (int a = 0; a < 8; ++a) av[a] = sWQ[tr * 8 + a][kk];
#pragma unroll
            for (int b = 0; b < 4; ++b) bv[b] = sWK[tc * 4 + b][kk];
#pragma unroll
            for (int a = 0; a < 8; ++a)
#pragma unroll
                for (int b = 0; b < 4; ++b) acc[a][b] = fmaf(av[a], bv[b], acc[a][b]);
        }
#pragma unroll
        for (int a = 0; a < 8; ++a) {
            float lp = 0.f;
#pragma unroll
            for (int b = 0; b < 4; ++b) {
                float e = __expf(acc[a][b] - 16.0f);
                sE[tr * 8 + a][tc * 4 + b] = e;
                lp += e;
            }
            lred[tr * 8 + a][tc] = lp;
        }
    }
    __syncthreads();
    if (t < 128) {
        float l = 0.f;
#pragma unroll
        for (int j = 0; j < 16; ++j) l += lred[t][j];
        LPART[(size_t)(ch * 8 + h) * 128 + t] = l;
    }

    {
        float acc2[8][2];
#pragma unroll
        for (int a = 0; a < 8; ++a) { acc2[a][0] = 0.f; acc2[a][1] = 0.f; }
#pragma unroll 4
        for (int kk = 0; kk < 64; ++kk) {
            float av[8], bv[2];
#pragma unroll
            for (int a = 0; a < 8; ++a) av[a] = sE[tr * 8 + a][kk];
            bv[0] = sWV[kk][tc * 2 + 0];
            bv[1] = sWV[kk][tc * 2 + 1];
#pragma unroll
            for (int a = 0; a < 8; ++a) {
                acc2[a][0] = fmaf(av[a], bv[0], acc2[a][0]);
                acc2[a][1] = fmaf(av[a], bv[1], acc2[a][1]);
            }
        }
#pragma unroll
        for (int a = 0; a < 8; ++a) {
            int b = tr * 8 + a;
            float* dst = &OPART[((size_t)(ch * 8 + h) * 128 + b) * 32 + tc * 2];
            dst[0] = acc2[a][0];
            dst[1] = acc2[a][1];
        }
    }
}

__global__ __launch_bounds__(256) void attn_reduce(
    const float* __restrict__ OPART, const float* __restrict__ LPART,
    const float* __restrict__ G, float* __restrict__ OMID)
{
    const int b = blockIdx.x;
    const int t = threadIdx.x;
    const int h = t >> 5, d = t & 31;
    float o = 0.f, l = 0.f;
    for (int ch = 0; ch < 128; ++ch) {
        o += OPART[((size_t)(ch * 8 + h) * 128 + b) * 32 + d];
        l += LPART[(size_t)(ch * 8 + h) * 128 + b];
    }
    int idx = b * 256 + h * 32 + d;
    OMID[idx] = G[idx] * (o / l);
}

// ============================ round-0 attention (fallback) ====================
__global__ __launch_bounds__(256) void attn_kernel(
    const float* __restrict__ WQ, const float* __restrict__ WK, const float* __restrict__ WV,
    const float* __restrict__ G, float* __restrict__ OMID)
{
    __shared__ float red[4][64][33];
    const int h = blockIdx.y;
    const int bl = threadIdx.x >> 6;
    const int lane = threadIdx.x & 63;
    const int b = blockIdx.x * 4 + bl;
    float q[32];
    {
        const float* wq = &WQ[(size_t)b * 256 + h * 32];
#pragma unroll
        for (int j = 0; j < 8; ++j) {
            float4 v = *(const float4*)&wq[j * 4];
            q[j * 4 + 0] = v.x; q[j * 4 + 1] = v.y; q[j * 4 + 2] = v.z; q[j * 4 + 3] = v.w;
        }
    }
    float o[32];
#pragma unroll
    for (int d = 0; d < 32; ++d) o[d] = 0.f;
    float l = 0.f;
#pragma unroll 2
    for (int s = lane; s < 8192; s += 64) {
        const float* kr = &WK[(size_t)s * 256 + h * 32];
        float s0 = 0, s1 = 0, s2 = 0, s3 = 0;
#pragma unroll
        for (int j = 0; j < 8; ++j) {
            float4 kv = *(const float4*)&kr[j * 4];
            s0 = fmaf(q[j * 4 + 0], kv.x, s0);
            s1 = fmaf(q[j * 4 + 1], kv.y, s1);
            s2 = fmaf(q[j * 4 + 2], kv.z, s2);
            s3 = fmaf(q[j * 4 + 3], kv.w, s3);
        }
        float e = __expf((s0 + s1) + (s2 + s3) - 16.0f);
        l += e;
        const float* vr = &WV[(size_t)s * 256 + h * 32];
#pragma unroll
        for (int j = 0; j < 8; ++j) {
            float4 vv = *(const float4*)&vr[j * 4];
            o[j * 4 + 0] = fmaf(e, vv.x, o[j * 4 + 0]);
            o[j * 4 + 1] = fmaf(e, vv.y, o[j * 4 + 1]);
            o[j * 4 + 2] = fmaf(e, vv.z, o[j * 4 + 2]);
            o[j * 4 + 3] = fmaf(e, vv.w, o[j * 4 + 3]);
        }
    }
#pragma unroll
    for (int d = 0; d < 32; ++d) red[bl][lane][d] = o[d];
    red[bl][lane][32] = l;
    __syncthreads();
    if (threadIdx.x < 128) {
        int bl2 = threadIdx.x >> 5;
        int d = threadIdx.x & 31;
        float os = 0.f, ls = 0.f;
#pragma unroll 8
        for (int ln = 0; ln < 64; ++ln) {
            os += red[bl2][ln][d];
            ls += red[bl2][ln][32];
        }
        int b2 = blockIdx.x * 4 + bl2;
        int idx = b2 * 256 + h * 32 + d;
        OMID[idx] = G[idx] * (os / ls);
    }
}

extern "C" void kernel_launch(void* const* d_in, const int* in_sizes, int n_in,
                              void* d_out, int out_size, void* d_ws, size_t ws_size,
                              hipStream_t stream) {
    const float* q    = (const float*)d_in[0];
    const float* k    = (const float*)d_in[1];
    const float* v    = (const float*)d_in[2];
    const float* q_sw = (const float*)d_in[3];
    const float* q_bw = (const float*)d_in[4];
    const float* q_bb = (const float*)d_in[5];
    const float* k_sw = (const float*)d_in[6];
    const float* k_bw = (const float*)d_in[7];
    const float* k_bb = (const float*)d_in[8];
    const float* v_sw = (const float*)d_in[9];
    const float* v_bw = (const float*)d_in[10];
    const float* v_bb = (const float*)d_in[11];
    const float* g_sw = (const float*)d_in[12];
    const float* g_bw = (const float*)d_in[13];
    const float* g_bb = (const float*)d_in[14];
    const float* o_sw = (const float*)d_in[15];
    const float* o_bw = (const float*)d_in[16];
    const float* o_bb = (const float*)d_in[17];

    float* ws = (float*)d_ws;
    float* wk = ws;                         // 8192*256 (fallback fp32)
    float* wv = ws + 2097152;               // 8192*256 (fallback fp32)
    float* wq = ws + 4194304;               // 128*256 (fallback fp32)
    float* gb = ws + 4227072;               // 128*256 (fallback)
    float* om = ws + 4259840;               // 128*256
    short* Bk = (short*)(ws + 4292608);     // 256*2304 bf16
    short* Bv = (short*)(ws + 4587520);     // 256*2304 bf16
    float* Opart = ws + 4882432;            // 128*8*128*32
    float* Lpart = ws + 9076736;            // 128*8*128
    float* PART = Opart;                    // aliased, disjoint lifetime
    short* A0 = (short*)(ws + 9207808);     // 8192*2304 bf16
    short* A1 = (short*)(ws + 18644992);    // 8192*2304 bf16
    short* GPk0 = (short*)(ws + 28082176);  // 8192*256 bf16 partial
    short* GPk1 = (short*)(ws + 29130752);
    short* GPv0 = (short*)(ws + 30179328);
    short* GPv1 = (short*)(ws + 31227904);
    short* WQb  = (short*)(ws + 32276480);  // 128*256 bf16 (fallback)
    short* Bq   = (short*)(ws + 32292864);  // 256*2304 bf16
    short* Bg   = (short*)(ws + 32587776);  // 256*2304 bf16
    short* Aq   = (short*)(ws + 32882688);  // 128*2304 bf16
    short* GPq0 = (short*)(ws + 33030144);  // 128*256 bf16 = 16384 floats each
    short* GPq1 = (short*)(ws + 33046528);
    short* GPg0 = (short*)(ws + 33062912);
    short* GPg1 = (short*)(ws + 33079296);
    short* Abuf = (short*)Opart;            // fallback aliased A
    float* out = (float*)d_out;

    const bool can_mfma   = ws_size >= (size_t)4882432 * 4;
    const bool can_bigger = ws_size >= (size_t)(4882432 + 9437184) * 4;
    const bool can_huge   = ws_size >= (size_t)33095680 * 4;   // ~132.4 MB

    dim3 blk(256);
    if (can_huge) {
        prep_basis<<<dim3(17088), blk, 0, stream>>>(
            k, v, q, A0, A1, Aq,
            k_sw, k_bw, Bk, v_sw, v_bw, Bv,
            q_sw, q_bw, Bq, g_sw, g_bw, Bg);
        stage2<<<dim3(520), blk, 0, stream>>>(
            A0, A1, Aq, Bk, Bv, Bq, Bg, k_bb, v_bb, q_bb, g_bb,
            GPk0, GPk1, GPv0, GPv1, GPq0, GPq1, GPg0, GPg1);
        attn_mfma<<<dim3(128, 8), blk, 0, stream>>>(GPq0, GPq1, GPk0, GPk1, GPv0, GPv1,
                                                    Opart, Lpart);
        attn_reduce2<<<dim3(128, 8), blk, 0, stream>>>(Opart, Lpart, GPg0, GPg1, om);
        fastkan_splitk<<<dim3(8, 9, 1), blk, 0, stream>>>(om, o_sw, o_bw, o_sw, o_bw, PART);
        reduce_kernel<0><<<dim3(128), blk, 0, stream>>>(PART, o_bb, out);
    } else if (can_bigger) {
        prep_kernel<<<dim3(36, 4, 2), blk, 0, stream>>>(k_sw, k_bw, Bk, v_sw, v_bw, Bv);
        fastkan_splitk<<<dim3(8, 9, 2), blk, 0, stream>>>(q, q_sw, q_bw, g_sw, g_bw, PART);
        reduce_qg<0><<<dim3(128, 2), blk, 0, stream>>>(PART, q_bb, g_bb, wq, gb, WQb);
        basis_gen2<<<dim3(8192, 1), blk, 0, stream>>>(k, k, Abuf, Abuf);
        gemm_tile<<<dim3(128, 4), blk, 0, stream>>>(Abuf, Bk, k_bb, wk);
        basis_gen2<<<dim3(8192, 1), blk, 0, stream>>>(v, v, Abuf, Abuf);
        gemm_tile<<<dim3(128, 4), blk, 0, stream>>>(Abuf, Bv, v_bb, wv);
        attn_chunk<<<dim3(128, 8), blk, 0, stream>>>(wq, wk, wv, Opart, Lpart);
        attn_reduce<<<dim3(128), blk, 0, stream>>>(Opart, Lpart, gb, om);
        fastkan_splitk<<<dim3(8, 9, 1), blk, 0, stream>>>(om, o_sw, o_bw, o_sw, o_bw, PART);
        reduce_kernel<0><<<dim3(128), blk, 0, stream>>>(PART, o_bb, out);
    } else {
        fastkan_kernel<64, 64, 0><<<dim3(128, 4), blk, 0, stream>>>(k, k_sw, k_bw, k_bb, wk);
        fastkan_kernel<64, 64, 0><<<dim3(128, 4), blk, 0, stream>>>(v, v_sw, v_bw, v_bb, wv);
        fastkan_kernel<32, 32, 1><<<dim3(4, 8), blk, 0, stream>>>(q, q_sw, q_bw, q_bb, wq);
        fastkan_kernel<32, 32, 2><<<dim3(4, 8), blk, 0, stream>>>(q, g_sw, g_bw, g_bb, gb);
        attn_kernel<<<dim3(32, 8), blk, 0, stream>>>(wq, wk, wv, gb, om);
        fastkan_kernel<32, 32, 0><<<dim3(4, 8), blk, 0, stream>>>(om, o_sw, o_bw, o_bb, out);
    }
}